// Round 1
// baseline (1305.758 us; speedup 1.0000x reference)
//
#include <hip/hip_runtime.h>
#include <math.h>

#define NB   2
#define LVL  4
#define QQ   4096
#define LEN  16384   // LVL*QQ
#define CH   256
#define NH   8
#define DD   32
#define PP   4
#define HL   64
#define WL   64

// out[m, t] = sum_k in[m,k] * W[k,t] + b[t]   (8 rows per block, 256 threads)
__global__ __launch_bounds__(256) void rowgemm256(const float* __restrict__ in,
                                                  const float* __restrict__ W,
                                                  const float* __restrict__ b,
                                                  float* __restrict__ out)
{
    __shared__ float s_in[8][CH];
    const int t  = threadIdx.x;
    const int m0 = blockIdx.x * 8;
    #pragma unroll
    for (int r = 0; r < 8; ++r)
        s_in[r][t] = in[(size_t)(m0 + r) * CH + t];
    __syncthreads();

    float acc[8] = {0.f,0.f,0.f,0.f,0.f,0.f,0.f,0.f};
    for (int k = 0; k < CH; ++k) {
        const float w = W[(size_t)k * CH + t];
        #pragma unroll
        for (int r = 0; r < 8; ++r)
            acc[r] += s_in[r][k] * w;
    }
    const float bias = b[t];
    #pragma unroll
    for (int r = 0; r < 8; ++r)
        out[(size_t)(m0 + r) * CH + t] = acc[r] + bias;
}

// One block per (n, iq).  Computes offsets/attn for all 4 target levels,
// softmax, then bilinear sampling into out_pre[n, iq, h*32+d].
__global__ __launch_bounds__(256) void fused_sample(
    const float* __restrict__ seq_query,   // (LVL, LVL, NB, QQ, CH)
    const float* __restrict__ ref_pts,     // (NB, LEN, LVL, 2)
    const float* __restrict__ W_off,       // (LVL, CH, 64)
    const float* __restrict__ b_off,       // (LVL, 64)
    const float* __restrict__ W_attn,      // (LVL, CH, 32)
    const float* __restrict__ b_attn,      // (LVL, 32)
    const float* __restrict__ value,       // (NB, LEN, NH, DD)
    float* __restrict__ out_pre)           // (NB, LEN, CH)
{
    const int bid = blockIdx.x;      // n * LEN + iq
    const int n   = bid / LEN;
    const int iq  = bid % LEN;
    const int i   = iq / QQ;         // query's own level (selects W/b)
    const int q   = iq % QQ;
    const int t   = threadIdx.x;

    __shared__ float s_sq [LVL][CH];   // 4 KB
    __shared__ float s_off[LVL][64];
    __shared__ float s_aw [LVL][32];

    // stage the 4 per-level query rows
    #pragma unroll
    for (int j = 0; j < LVL; ++j)
        s_sq[j][t] = seq_query[((((size_t)i * LVL + j) * NB + n) * QQ + q) * CH + t];
    __syncthreads();

    // 384 dot products: u -> (j = u/96, col = u%96); col<64 => offset, else attn
    for (int u = t; u < 384; u += 256) {
        const int j   = u / 96;
        const int col = u % 96;
        float acc = 0.f;
        if (col < 64) {
            const float* w = W_off + (size_t)i * CH * 64 + col;
            for (int c = 0; c < CH; ++c)
                acc += s_sq[j][c] * w[(size_t)c * 64];
            s_off[j][col] = acc + b_off[i * 64 + col];
        } else {
            const int cc = col - 64;
            const float* w = W_attn + (size_t)i * CH * 32 + cc;
            for (int c = 0; c < CH; ++c)
                acc += s_sq[j][c] * w[(size_t)c * 32];
            s_aw[j][cc] = acc + b_attn[i * 32 + cc];
        }
    }
    __syncthreads();

    // softmax over the 16 (j,p) values per head
    if (t < NH) {
        const int h = t;
        float m = -1e30f;
        #pragma unroll
        for (int j = 0; j < LVL; ++j)
            #pragma unroll
            for (int p = 0; p < PP; ++p)
                m = fmaxf(m, s_aw[j][h * 4 + p]);
        float e[16];
        float s = 0.f;
        #pragma unroll
        for (int j = 0; j < LVL; ++j)
            #pragma unroll
            for (int p = 0; p < PP; ++p) {
                const float v = __expf(s_aw[j][h * 4 + p] - m);
                e[j * 4 + p] = v;
                s += v;
            }
        const float inv = 1.f / s;
        #pragma unroll
        for (int j = 0; j < LVL; ++j)
            #pragma unroll
            for (int p = 0; p < PP; ++p)
                s_aw[j][h * 4 + p] = e[j * 4 + p] * inv;
    }
    __syncthreads();

    // bilinear sampling: thread = (head h, channel d)
    const int h = t >> 5;
    const int d = t & 31;
    float acc = 0.f;
    #pragma unroll
    for (int l = 0; l < LVL; ++l) {
        const float rx = ref_pts[(((size_t)n * LEN + iq) * LVL + l) * 2 + 0];
        const float ry = ref_pts[(((size_t)n * LEN + iq) * LVL + l) * 2 + 1];
        const float* vl = value + (((size_t)n * LEN + (size_t)l * QQ) * NH + h) * DD + d;
        #pragma unroll
        for (int p = 0; p < PP; ++p) {
            const float ox = s_off[l][h * 8 + p * 2 + 0];
            const float oy = s_off[l][h * 8 + p * 2 + 1];
            const float aw = s_aw [l][h * 4 + p];
            const float lx = rx + ox * (1.f / WL);
            const float ly = ry + oy * (1.f / HL);
            const float px = lx * WL - 0.5f;
            const float py = ly * HL - 0.5f;
            const float x0f = floorf(px), y0f = floorf(py);
            const float dx = px - x0f,   dy = py - y0f;
            const int   x0 = (int)x0f,   y0 = (int)y0f;

            float sampv = 0.f;
            #pragma unroll
            for (int cy = 0; cy < 2; ++cy) {
                #pragma unroll
                for (int cx = 0; cx < 2; ++cx) {
                    const int gx = x0 + cx;
                    const int gy = y0 + cy;
                    const bool valid = (gx >= 0) && (gx < WL) && (gy >= 0) && (gy < HL);
                    const int cgx = min(max(gx, 0), WL - 1);
                    const int cgy = min(max(gy, 0), HL - 1);
                    const float wx = cx ? dx : (1.f - dx);
                    const float wy = cy ? dy : (1.f - dy);
                    const float g = vl[(size_t)(cgy * WL + cgx) * (NH * DD)];
                    sampv += valid ? g * (wx * wy) : 0.f;
                }
            }
            acc += aw * sampv;
        }
    }
    out_pre[((size_t)n * LEN + iq) * CH + h * DD + d] = acc;
}

extern "C" void kernel_launch(void* const* d_in, const int* in_sizes, int n_in,
                              void* d_out, int out_size, void* d_ws, size_t ws_size,
                              hipStream_t stream) {
    const float* seq_query = (const float*)d_in[0];
    const float* ref_pts   = (const float*)d_in[1];
    const float* input_fl  = (const float*)d_in[2];
    const float* W_off     = (const float*)d_in[3];
    const float* b_off     = (const float*)d_in[4];
    const float* W_attn    = (const float*)d_in[5];
    const float* b_attn    = (const float*)d_in[6];
    const float* W_val     = (const float*)d_in[7];
    const float* b_val     = (const float*)d_in[8];
    const float* W_out     = (const float*)d_in[9];
    const float* b_out     = (const float*)d_in[10];
    // d_in[11]/d_in[12]: spatial shapes / level starts — compile-time constants here

    float* out = (float*)d_out;
    float* ws  = (float*)d_ws;

    float* value   = ws;                       // NB*LEN*CH = 8388608 floats
    float* out_pre = ws + (size_t)NB * LEN * CH;

    const int nrows = NB * LEN;                // 32768

    // 1) value projection
    rowgemm256<<<nrows / 8, 256, 0, stream>>>(input_fl, W_val, b_val, value);

    // 2) fused offsets/attn/softmax/bilinear sampling
    fused_sample<<<NB * LEN, 256, 0, stream>>>(seq_query, ref_pts, W_off, b_off,
                                               W_attn, b_attn, value, out_pre);

    // 3) output projection
    rowgemm256<<<nrows / 8, 256, 0, stream>>>(out_pre, W_out, b_out, out);
}

// Round 2
// 524.826 us; speedup vs baseline: 2.4880x; 2.4880x over previous
//
#include <hip/hip_runtime.h>
#include <math.h>

#define NB   2
#define LVL  4
#define QQ   4096
#define LEN  16384   // LVL*QQ
#define CH   256
#define NH   8
#define DD   32
#define PP   4
#define HL   64
#define WL   64

// out[m, t] = sum_k in[m,k] * W[k,t] + b[t]   (8 rows per block, 256 threads)
__global__ __launch_bounds__(256) void rowgemm256(const float* __restrict__ in,
                                                  const float* __restrict__ W,
                                                  const float* __restrict__ b,
                                                  float* __restrict__ out)
{
    __shared__ float s_in[8][CH];
    const int t  = threadIdx.x;
    const int m0 = blockIdx.x * 8;
    #pragma unroll
    for (int r = 0; r < 8; ++r)
        s_in[r][t] = in[(size_t)(m0 + r) * CH + t];
    __syncthreads();

    float acc[8] = {0.f,0.f,0.f,0.f,0.f,0.f,0.f,0.f};
    for (int k = 0; k < CH; ++k) {
        const float w = W[(size_t)k * CH + t];
        #pragma unroll
        for (int r = 0; r < 8; ++r)
            acc[r] += s_in[r][k] * w;
    }
    const float bias = b[t];
    #pragma unroll
    for (int r = 0; r < 8; ++r)
        out[(size_t)(m0 + r) * CH + t] = acc[r] + bias;
}

// Offset+attn projection as 16 GEMMs (one per (i,j)): 8192 rows x 256 x 96.
// Output layout: proj[((n*LVL+i)*QQ+q)*LVL + j][96]  (= proj[bid][j*96+col] for
// bid = n*LEN + i*QQ + q) with col<64 = offsets, col>=64 = attn logits.
#define PROWS 32
__global__ __launch_bounds__(384) void proj_gemm(
    const float* __restrict__ seq_query,   // (LVL_i, LVL_j, NB, QQ, CH)
    const float* __restrict__ W_off,       // (LVL, CH, 64)
    const float* __restrict__ b_off,       // (LVL, 64)
    const float* __restrict__ W_attn,      // (LVL, CH, 32)
    const float* __restrict__ b_attn,      // (LVL, 32)
    float* __restrict__ proj)
{
    __shared__ float s_in[PROWS][CH];      // 32 KB
    const int t  = threadIdx.x;
    const int ij = blockIdx.y;
    const int i  = ij >> 2;
    const int j  = ij & 3;
    const int r0 = blockIdx.x * PROWS;     // flat (n,q) row base, 0..8191

    const float* src = seq_query + ((size_t)ij * (NB * QQ) + r0) * CH;
    for (int u = t; u < PROWS * CH; u += 384)
        s_in[u >> 8][u & 255] = src[u];
    __syncthreads();

    const int col = t % 96;
    const int grp = t / 96;                // 0..3 -> rows grp*8 .. grp*8+7
    const float* wp;
    int stride;
    float bias;
    if (col < 64) {
        wp = W_off + (size_t)i * CH * 64 + col;
        stride = 64;
        bias = b_off[i * 64 + col];
    } else {
        const int cc = col - 64;
        wp = W_attn + (size_t)i * CH * 32 + cc;
        stride = 32;
        bias = b_attn[i * 32 + cc];
    }

    float acc[8] = {0.f,0.f,0.f,0.f,0.f,0.f,0.f,0.f};
    for (int k = 0; k < CH; ++k) {
        const float w = wp[(size_t)k * stride];
        #pragma unroll
        for (int r = 0; r < 8; ++r)
            acc[r] += s_in[grp * 8 + r][k] * w;
    }

    #pragma unroll
    for (int r = 0; r < 8; ++r) {
        const int row = r0 + grp * 8 + r;          // flat (n,q)
        const int n = row >> 12;
        const int q = row & 4095;
        const size_t o = ((((size_t)n * LVL + i) * QQ + q) * LVL + j) * 96 + col;
        proj[o] = acc[r] + bias;
    }
}

// One block per (n, iq): softmax + corner-table precompute + gather.
__global__ __launch_bounds__(256) void sampler(
    const float* __restrict__ proj,        // (NB*LEN, 384)
    const float* __restrict__ ref_pts,     // (NB, LEN, LVL, 2)
    const float* __restrict__ value,       // (NB, LEN, NH, DD)
    float* __restrict__ out_pre)           // (NB, LEN, CH)
{
    const int bid = blockIdx.x;            // n*LEN + iq
    const int n   = bid >> 14;
    const int t   = threadIdx.x;

    __shared__ float s_proj[LVL][96];
    __shared__ float s_ref [LVL][2];
    __shared__ float s_aw  [LVL][NH * PP];
    __shared__ int   s_cidx[LVL][PP][NH][4];
    __shared__ float s_cw  [LVL][PP][NH][4];

    const float* pr = proj + (size_t)bid * 384;
    for (int u = t; u < 384; u += 256)
        ((float*)s_proj)[u] = pr[u];
    if (t < 8)
        s_ref[t >> 1][t & 1] = ref_pts[((size_t)bid * LVL + (t >> 1)) * 2 + (t & 1)];
    __syncthreads();

    if (t < 8) {
        // softmax for head t over 16 (j,p) logits
        const int h = t;
        float m = -1e30f;
        #pragma unroll
        for (int j = 0; j < LVL; ++j)
            #pragma unroll
            for (int p = 0; p < PP; ++p)
                m = fmaxf(m, s_proj[j][64 + h * 4 + p]);
        float e[16];
        float s = 0.f;
        #pragma unroll
        for (int j = 0; j < LVL; ++j)
            #pragma unroll
            for (int p = 0; p < PP; ++p) {
                const float v = __expf(s_proj[j][64 + h * 4 + p] - m);
                e[j * 4 + p] = v;
                s += v;
            }
        const float inv = 1.f / s;
        #pragma unroll
        for (int j = 0; j < LVL; ++j)
            #pragma unroll
            for (int p = 0; p < PP; ++p)
                s_aw[j][h * 4 + p] = e[j * 4 + p] * inv;
    } else if (t >= 128) {
        // corner tables for (l,p,h)
        const int u = t - 128;
        const int l = u >> 5;
        const int p = (u >> 3) & 3;
        const int h = u & 7;
        const float ox = s_proj[l][h * 8 + p * 2 + 0];
        const float oy = s_proj[l][h * 8 + p * 2 + 1];
        const float px = s_ref[l][0] * (float)WL + ox - 0.5f;
        const float py = s_ref[l][1] * (float)HL + oy - 0.5f;
        const float x0f = floorf(px), y0f = floorf(py);
        const float dx = px - x0f,   dy = py - y0f;
        const int   x0 = (int)x0f,   y0 = (int)y0f;
        #pragma unroll
        for (int c = 0; c < 4; ++c) {
            const int cx = c & 1, cy = c >> 1;
            const int gx = x0 + cx, gy = y0 + cy;
            const bool valid = ((unsigned)gx < (unsigned)WL) && ((unsigned)gy < (unsigned)HL);
            const int cgx = min(max(gx, 0), WL - 1);
            const int cgy = min(max(gy, 0), HL - 1);
            const float w = (cx ? dx : 1.f - dx) * (cy ? dy : 1.f - dy);
            s_cidx[l][p][h][c] = cgy * WL + cgx;
            s_cw  [l][p][h][c] = valid ? w : 0.f;
        }
    }
    __syncthreads();

    const int h = t >> 5;
    const int d = t & 31;
    const float* vb = value + ((size_t)n * LEN) * CH + h * DD + d;
    float acc = 0.f;
    #pragma unroll
    for (int l = 0; l < LVL; ++l) {
        const float* vl = vb + (size_t)l * QQ * CH;
        #pragma unroll
        for (int p = 0; p < PP; ++p) {
            const float aw = s_aw[l][h * 4 + p];
            float s = 0.f;
            #pragma unroll
            for (int c = 0; c < 4; ++c)
                s += s_cw[l][p][h][c] * vl[(size_t)s_cidx[l][p][h][c] * CH];
            acc += aw * s;
        }
    }
    out_pre[(size_t)bid * CH + h * DD + d] = acc;
}

extern "C" void kernel_launch(void* const* d_in, const int* in_sizes, int n_in,
                              void* d_out, int out_size, void* d_ws, size_t ws_size,
                              hipStream_t stream) {
    const float* seq_query = (const float*)d_in[0];
    const float* ref_pts   = (const float*)d_in[1];
    const float* input_fl  = (const float*)d_in[2];
    const float* W_off     = (const float*)d_in[3];
    const float* b_off     = (const float*)d_in[4];
    const float* W_attn    = (const float*)d_in[5];
    const float* b_attn    = (const float*)d_in[6];
    const float* W_val     = (const float*)d_in[7];
    const float* b_val     = (const float*)d_in[8];
    const float* W_out     = (const float*)d_in[9];
    const float* b_out     = (const float*)d_in[10];

    float* out = (float*)d_out;
    float* ws  = (float*)d_ws;

    float* value   = ws;                                   // 33.5 MB
    float* proj    = value + (size_t)NB * LEN * CH;        // 50.3 MB
    float* out_pre = proj  + (size_t)NB * LEN * 384;       // 33.5 MB

    const int nrows = NB * LEN;                            // 32768

    // 1) value projection
    rowgemm256<<<nrows / 8, 256, 0, stream>>>(input_fl, W_val, b_val, value);

    // 2) offset/attn projection GEMM
    proj_gemm<<<dim3((NB * QQ) / PROWS, LVL * LVL), 384, 0, stream>>>(
        seq_query, W_off, b_off, W_attn, b_attn, proj);

    // 3) softmax + bilinear sampling
    sampler<<<nrows, 256, 0, stream>>>(proj, ref_pts, value, out_pre);

    // 4) output projection
    rowgemm256<<<nrows / 8, 256, 0, stream>>>(out_pre, W_out, b_out, out);
}

// Round 3
// 190.932 us; speedup vs baseline: 6.8389x; 2.7488x over previous
//
#include <hip/hip_runtime.h>
#include <math.h>

#define NB   2
#define LVL  4
#define QQ   4096
#define LEN  16384   // LVL*QQ
#define CH   256
#define NH   8
#define DD   32
#define PP   4
#define HL   64
#define WL   64

typedef float f32x4 __attribute__((ext_vector_type(4)));
typedef short s16x8 __attribute__((ext_vector_type(8)));

__device__ __forceinline__ unsigned short f2bf(float f) {
    union { float f; unsigned u; } v; v.f = f;
    unsigned r = v.u + 0x7FFFu + ((v.u >> 16) & 1u);
    return (unsigned short)(r >> 16);
}
__device__ __forceinline__ float bf2f(unsigned short b) {
    union { unsigned u; float f; } v; v.u = ((unsigned)b) << 16; return v.f;
}

// Convert weights to bf16, transposed to [N][K], 16B-groups XOR-swizzled:
// WT[c][ (g&~7)|((g&7)^(c&7)) *8 + e ] = W[g*8+e][c]
__global__ __launch_bounds__(256) void prep_w(
    const float* __restrict__ W_val, const float* __restrict__ W_out,
    const float* __restrict__ W_off, const float* __restrict__ W_attn,
    short* __restrict__ WT_val, short* __restrict__ WT_out, short* __restrict__ WT_proj)
{
    const int id = blockIdx.x * 256 + threadIdx.x;   // 0 .. 229375
    if (id < 131072) {
        const int which = id >> 16;          // 0: W_val, 1: W_out
        const int u = id & 65535;
        const int c = u >> 8;                // WT row (output col), 0..255
        const int p = u & 255;               // stored position
        const int gp = p >> 3, e = p & 7;
        const int g = (gp & ~7) | ((gp & 7) ^ (c & 7));
        const int k = g * 8 + e;
        const float* W = which ? W_out : W_val;
        short* WT = which ? WT_out : WT_val;
        WT[(size_t)c * 256 + p] = (short)f2bf(W[(size_t)k * 256 + c]);
    } else {
        const int u = id - 131072;           // 0 .. 98303
        const int i = u / (96 * 256);
        const int r = u % (96 * 256);
        const int c = r >> 8;                // 0..95
        const int p = r & 255;
        const int gp = p >> 3, e = p & 7;
        const int g = (gp & ~7) | ((gp & 7) ^ (c & 7));
        const int k = g * 8 + e;
        float w;
        if (c < 64) w = W_off[((size_t)i * 256 + k) * 64 + c];
        else        w = W_attn[((size_t)i * 256 + k) * 32 + (c - 64)];
        WT_proj[((size_t)i * 96 + c) * 256 + p] = (short)f2bf(w);
    }
}

// MFMA GEMM: C[M,N] = A[M,256] @ W[256,N] + bias.  BM=128, BK=64, B LDS-resident.
// MODE 0: A fp32, C bf16 (value proj, N=256 via blockIdx.y slices of 64)
// MODE 1: A bf16, C fp32 (out proj)
// MODE 2: A fp32 = seq_query[ij], C fp32 proj layout, N=96 (blockIdx.y = ij)
template<int MODE, int BN, int WN, int MR, int NR>
__global__ __launch_bounds__(256) void gemm_mfma(
    const void* __restrict__ Ain, const short* __restrict__ WT,
    const float* __restrict__ bias, const float* __restrict__ bias2,
    void* __restrict__ Cout)
{
    __shared__ short sA[128 * 64];     // 16 KB, XOR-swizzled
    __shared__ short sB[BN * 256];     // pre-swizzled rows [col][K]
    const int t    = threadIdx.x;
    const int lane = t & 63;
    const int wave = t >> 6;
    const int m0   = blockIdx.x * 128;

    int i = 0, j = 0, n0 = 0;
    const float*          Af = (const float*)Ain;
    const unsigned short* Ab = (const unsigned short*)Ain;
    const short*          wt = WT;
    if (MODE == 2) {
        const int ij = blockIdx.y;
        i = ij >> 2; j = ij & 3;
        Af += (size_t)ij * (NB * QQ) * CH;
        wt += (size_t)i * 96 * 256;
    } else {
        n0 = blockIdx.y * BN;
        wt += (size_t)n0 * 256;
    }

    // stage B once (whole K), linear copy of pre-swizzled rows
    for (int u = t; u < BN * 32; u += 256)
        *(int4*)(sB + (size_t)u * 8) = *(const int4*)(wt + (size_t)u * 8);

    f32x4 acc[MR][NR];
    #pragma unroll
    for (int m = 0; m < MR; ++m)
        #pragma unroll
        for (int n = 0; n < NR; ++n)
            acc[m][n] = (f32x4){0.f, 0.f, 0.f, 0.f};

    const int wr = wave / WN;
    const int wc = wave % WN;
    const int rbase = wr * MR * 16;
    const int cbase = wc * NR * 16;
    const int lr  = lane & 15;
    const int lkg = lane >> 4;

    for (int ko = 0; ko < 4; ++ko) {
        // stage A[128][64] bf16 swizzled (fused convert for fp32 sources)
        #pragma unroll
        for (int v = 0; v < 4; ++v) {
            const int u = t + v * 256;
            const int row = u >> 3, g = u & 7;
            char* dst = (char*)sA + row * 128 + ((g ^ (row & 7)) << 4);
            if (MODE == 1) {
                *(int4*)dst = *(const int4*)(Ab + (size_t)(m0 + row) * CH + ko * 64 + g * 8);
            } else {
                const float* sp = Af + (size_t)(m0 + row) * CH + ko * 64 + g * 8;
                const float4 f0 = *(const float4*)sp;
                const float4 f1 = *(const float4*)(sp + 4);
                s16x8 w;
                w[0] = (short)f2bf(f0.x); w[1] = (short)f2bf(f0.y);
                w[2] = (short)f2bf(f0.z); w[3] = (short)f2bf(f0.w);
                w[4] = (short)f2bf(f1.x); w[5] = (short)f2bf(f1.y);
                w[6] = (short)f2bf(f1.z); w[7] = (short)f2bf(f1.w);
                *(s16x8*)dst = w;
            }
        }
        __syncthreads();
        #pragma unroll
        for (int s = 0; s < 2; ++s) {
            s16x8 afr[MR], bfr[NR];
            #pragma unroll
            for (int m = 0; m < MR; ++m) {
                const int row = rbase + m * 16 + lr;
                afr[m] = *(const s16x8*)((const char*)sA + row * 128 +
                                         (((s * 4 + lkg) ^ (row & 7)) << 4));
            }
            #pragma unroll
            for (int n = 0; n < NR; ++n) {
                const int col = cbase + n * 16 + lr;
                const int g  = ko * 8 + s * 4 + lkg;
                const int gp = (g & ~7) | ((g & 7) ^ (col & 7));
                bfr[n] = *(const s16x8*)((const char*)sB + (size_t)col * 512 + (gp << 4));
            }
            #pragma unroll
            for (int m = 0; m < MR; ++m)
                #pragma unroll
                for (int n = 0; n < NR; ++n)
                    acc[m][n] = __builtin_amdgcn_mfma_f32_16x16x32_bf16(afr[m], bfr[n], acc[m][n], 0, 0, 0);
        }
        __syncthreads();
    }

    // epilogue: C/D mapping col=lane&15, row=(lane>>4)*4+reg
    #pragma unroll
    for (int m = 0; m < MR; ++m) {
        #pragma unroll
        for (int n = 0; n < NR; ++n) {
            #pragma unroll
            for (int r = 0; r < 4; ++r) {
                const int row = m0 + rbase + m * 16 + (lane >> 4) * 4 + r;
                const int col = cbase + n * 16 + lr;
                const float v = acc[m][n][r];
                if (MODE == 0) {
                    ((unsigned short*)Cout)[(size_t)row * CH + n0 + col] = f2bf(v + bias[n0 + col]);
                } else if (MODE == 1) {
                    ((float*)Cout)[(size_t)row * CH + n0 + col] = v + bias[n0 + col];
                } else {
                    const int nb = row >> 12, q = row & 4095;
                    const float bc = (col < 64) ? bias[i * 64 + col] : bias2[i * 32 + (col - 64)];
                    ((float*)Cout)[((((size_t)nb * LVL + i) * QQ + q) * LVL + j) * 96 + col] = v + bc;
                }
            }
        }
    }
}

// One block per (n, iq): softmax + corner-table precompute + gather (bf16 value).
__global__ __launch_bounds__(256) void sampler(
    const float* __restrict__ proj,              // (NB*LEN, 384)
    const float* __restrict__ ref_pts,           // (NB, LEN, LVL, 2)
    const unsigned short* __restrict__ value,    // (NB, LEN, 256) bf16
    unsigned short* __restrict__ out_pre)        // (NB, LEN, 256) bf16
{
    const int bid = blockIdx.x;            // n*LEN + iq
    const int n   = bid >> 14;
    const int t   = threadIdx.x;

    __shared__ float s_proj[LVL][96];
    __shared__ float s_ref [LVL][2];
    __shared__ float s_aw  [LVL][NH * PP];
    __shared__ int   s_cidx[LVL][PP][NH][4];
    __shared__ float s_cw  [LVL][PP][NH][4];

    const float* pr = proj + (size_t)bid * 384;
    for (int u = t; u < 384; u += 256)
        ((float*)s_proj)[u] = pr[u];
    if (t < 8)
        s_ref[t >> 1][t & 1] = ref_pts[((size_t)bid * LVL + (t >> 1)) * 2 + (t & 1)];
    __syncthreads();

    if (t < 8) {
        const int h = t;
        float m = -1e30f;
        #pragma unroll
        for (int j = 0; j < LVL; ++j)
            #pragma unroll
            for (int p = 0; p < PP; ++p)
                m = fmaxf(m, s_proj[j][64 + h * 4 + p]);
        float e[16];
        float s = 0.f;
        #pragma unroll
        for (int j = 0; j < LVL; ++j)
            #pragma unroll
            for (int p = 0; p < PP; ++p) {
                const float v = __expf(s_proj[j][64 + h * 4 + p] - m);
                e[j * 4 + p] = v;
                s += v;
            }
        const float inv = 1.f / s;
        #pragma unroll
        for (int j = 0; j < LVL; ++j)
            #pragma unroll
            for (int p = 0; p < PP; ++p)
                s_aw[j][h * 4 + p] = e[j * 4 + p] * inv;
    } else if (t >= 128) {
        const int u = t - 128;
        const int l = u >> 5;
        const int p = (u >> 3) & 3;
        const int h = u & 7;
        const float ox = s_proj[l][h * 8 + p * 2 + 0];
        const float oy = s_proj[l][h * 8 + p * 2 + 1];
        const float px = s_ref[l][0] * (float)WL + ox - 0.5f;
        const float py = s_ref[l][1] * (float)HL + oy - 0.5f;
        const float x0f = floorf(px), y0f = floorf(py);
        const float dx = px - x0f,   dy = py - y0f;
        const int   x0 = (int)x0f,   y0 = (int)y0f;
        #pragma unroll
        for (int c = 0; c < 4; ++c) {
            const int cx = c & 1, cy = c >> 1;
            const int gx = x0 + cx, gy = y0 + cy;
            const bool valid = ((unsigned)gx < (unsigned)WL) && ((unsigned)gy < (unsigned)HL);
            const int cgx = min(max(gx, 0), WL - 1);
            const int cgy = min(max(gy, 0), HL - 1);
            const float w = (cx ? dx : 1.f - dx) * (cy ? dy : 1.f - dy);
            s_cidx[l][p][h][c] = cgy * WL + cgx;
            s_cw  [l][p][h][c] = valid ? w : 0.f;
        }
    }
    __syncthreads();

    const int h = t >> 5;
    const int d = t & 31;
    const unsigned short* vb = value + ((size_t)n * LEN) * CH + h * DD + d;
    float acc = 0.f;
    #pragma unroll
    for (int l = 0; l < LVL; ++l) {
        const unsigned short* vl = vb + (size_t)l * QQ * CH;
        #pragma unroll
        for (int p = 0; p < PP; ++p) {
            const float aw = s_aw[l][h * 4 + p];
            float s = 0.f;
            #pragma unroll
            for (int c = 0; c < 4; ++c)
                s += s_cw[l][p][h][c] * bf2f(vl[(size_t)s_cidx[l][p][h][c] * CH]);
            acc += aw * s;
        }
    }
    out_pre[(size_t)bid * CH + h * DD + d] = f2bf(acc);
}

extern "C" void kernel_launch(void* const* d_in, const int* in_sizes, int n_in,
                              void* d_out, int out_size, void* d_ws, size_t ws_size,
                              hipStream_t stream) {
    const float* seq_query = (const float*)d_in[0];
    const float* ref_pts   = (const float*)d_in[1];
    const float* input_fl  = (const float*)d_in[2];
    const float* W_off     = (const float*)d_in[3];
    const float* b_off     = (const float*)d_in[4];
    const float* W_attn    = (const float*)d_in[5];
    const float* b_attn    = (const float*)d_in[6];
    const float* W_val     = (const float*)d_in[7];
    const float* b_val     = (const float*)d_in[8];
    const float* W_out     = (const float*)d_in[9];
    const float* b_out     = (const float*)d_in[10];

    float* out = (float*)d_out;

    unsigned short* value   = (unsigned short*)d_ws;                 // 16.8 MB
    unsigned short* out_pre = value + (size_t)NB * LEN * CH;         // 16.8 MB
    short* WT_val  = (short*)(out_pre + (size_t)NB * LEN * CH);      // 128 KB
    short* WT_out  = WT_val + 65536;                                 // 128 KB
    short* WT_proj = WT_out + 65536;                                 // 192 KB
    float* proj    = (float*)(WT_proj + 4 * 96 * 256);               // 50.3 MB

    // 0) weight prep: bf16, transposed, pre-swizzled
    prep_w<<<896, 256, 0, stream>>>(W_val, W_out, W_off, W_attn, WT_val, WT_out, WT_proj);

    // 1) value projection (fp32 in -> bf16 out)
    gemm_mfma<0, 64, 2, 4, 2><<<dim3(256, 4), 256, 0, stream>>>(
        input_fl, WT_val, b_val, nullptr, value);

    // 2) offset/attn projection (16 GEMMs, fp32 in -> fp32 proj)
    gemm_mfma<2, 96, 1, 2, 6><<<dim3(64, 16), 256, 0, stream>>>(
        seq_query, WT_proj, b_off, b_attn, proj);

    // 3) softmax + bilinear sampling (bf16 value -> bf16 out_pre)
    sampler<<<NB * LEN, 256, 0, stream>>>(proj, ref_pts, value, out_pre);

    // 4) output projection (bf16 in -> fp32 d_out)
    gemm_mfma<1, 64, 2, 4, 2><<<dim3(256, 4), 256, 0, stream>>>(
        out_pre, WT_out, b_out, nullptr, out);
}

// Round 4
// 190.667 us; speedup vs baseline: 6.8484x; 1.0014x over previous
//
#include <hip/hip_runtime.h>
#include <math.h>

#define NB   2
#define LVL  4
#define QQ   4096
#define LEN  16384   // LVL*QQ
#define CH   256
#define NH   8
#define DD   32
#define PP   4
#define HL   64
#define WL   64

typedef float f32x4 __attribute__((ext_vector_type(4)));
typedef short s16x8 __attribute__((ext_vector_type(8)));

__device__ __forceinline__ unsigned short f2bf(float f) {
    union { float f; unsigned u; } v; v.f = f;
    unsigned r = v.u + 0x7FFFu + ((v.u >> 16) & 1u);
    return (unsigned short)(r >> 16);
}
__device__ __forceinline__ float bflo(unsigned u) {
    union { unsigned x; float f; } v; v.x = u << 16; return v.f;
}
__device__ __forceinline__ float bfhi(unsigned u) {
    union { unsigned x; float f; } v; v.x = u & 0xFFFF0000u; return v.f;
}

// Convert weights to bf16, transposed to [N][K], 16B-groups XOR-swizzled:
// WT[c][ (g&~7)|((g&7)^(c&7)) *8 + e ] = W[g*8+e][c]
__global__ __launch_bounds__(256) void prep_w(
    const float* __restrict__ W_val, const float* __restrict__ W_out,
    const float* __restrict__ W_off, const float* __restrict__ W_attn,
    short* __restrict__ WT_val, short* __restrict__ WT_out, short* __restrict__ WT_proj)
{
    const int id = blockIdx.x * 256 + threadIdx.x;   // 0 .. 229375
    if (id < 131072) {
        const int which = id >> 16;          // 0: W_val, 1: W_out
        const int u = id & 65535;
        const int c = u >> 8;                // WT row (output col), 0..255
        const int p = u & 255;               // stored position
        const int gp = p >> 3, e = p & 7;
        const int g = (gp & ~7) | ((gp & 7) ^ (c & 7));
        const int k = g * 8 + e;
        const float* W = which ? W_out : W_val;
        short* WT = which ? WT_out : WT_val;
        WT[(size_t)c * 256 + p] = (short)f2bf(W[(size_t)k * 256 + c]);
    } else {
        const int u = id - 131072;           // 0 .. 98303
        const int i = u / (96 * 256);
        const int r = u % (96 * 256);
        const int c = r >> 8;                // 0..95
        const int p = r & 255;
        const int gp = p >> 3, e = p & 7;
        const int g = (gp & ~7) | ((gp & 7) ^ (c & 7));
        const int k = g * 8 + e;
        float w;
        if (c < 64) w = W_off[((size_t)i * 256 + k) * 64 + c];
        else        w = W_attn[((size_t)i * 256 + k) * 32 + (c - 64)];
        WT_proj[((size_t)i * 96 + c) * 256 + p] = (short)f2bf(w);
    }
}

// MFMA GEMM: C[M,N] = A[M,256] @ W[256,N] + bias.  BM=128, BK=64, B LDS-resident.
// MODE 0: A fp32, C bf16 (value proj, N=256 via blockIdx.y slices of 64)
// MODE 1: A bf16, C fp32 (out proj)
// MODE 2: A fp32 = seq_query[ij], C fp32 proj layout, N=96 (blockIdx.y = ij)
template<int MODE, int BN, int WN, int MR, int NR>
__global__ __launch_bounds__(256) void gemm_mfma(
    const void* __restrict__ Ain, const short* __restrict__ WT,
    const float* __restrict__ bias, const float* __restrict__ bias2,
    void* __restrict__ Cout)
{
    __shared__ short sA[128 * 64];     // 16 KB, XOR-swizzled
    __shared__ short sB[BN * 256];     // pre-swizzled rows [col][K]
    const int t    = threadIdx.x;
    const int lane = t & 63;
    const int wave = t >> 6;
    const int m0   = blockIdx.x * 128;

    int i = 0, j = 0, n0 = 0;
    const float*          Af = (const float*)Ain;
    const unsigned short* Ab = (const unsigned short*)Ain;
    const short*          wt = WT;
    if (MODE == 2) {
        const int ij = blockIdx.y;
        i = ij >> 2; j = ij & 3;
        Af += (size_t)ij * (NB * QQ) * CH;
        wt += (size_t)i * 96 * 256;
    } else {
        n0 = blockIdx.y * BN;
        wt += (size_t)n0 * 256;
    }

    // stage B once (whole K), linear copy of pre-swizzled rows
    for (int u = t; u < BN * 32; u += 256)
        *(int4*)(sB + (size_t)u * 8) = *(const int4*)(wt + (size_t)u * 8);

    f32x4 acc[MR][NR];
    #pragma unroll
    for (int m = 0; m < MR; ++m)
        #pragma unroll
        for (int n = 0; n < NR; ++n)
            acc[m][n] = (f32x4){0.f, 0.f, 0.f, 0.f};

    const int wr = wave / WN;
    const int wc = wave % WN;
    const int rbase = wr * MR * 16;
    const int cbase = wc * NR * 16;
    const int lr  = lane & 15;
    const int lkg = lane >> 4;

    for (int ko = 0; ko < 4; ++ko) {
        // stage A[128][64] bf16 swizzled (fused convert for fp32 sources)
        #pragma unroll
        for (int v = 0; v < 4; ++v) {
            const int u = t + v * 256;
            const int row = u >> 3, g = u & 7;
            char* dst = (char*)sA + row * 128 + ((g ^ (row & 7)) << 4);
            if (MODE == 1) {
                *(int4*)dst = *(const int4*)(Ab + (size_t)(m0 + row) * CH + ko * 64 + g * 8);
            } else {
                const float* sp = Af + (size_t)(m0 + row) * CH + ko * 64 + g * 8;
                const float4 f0 = *(const float4*)sp;
                const float4 f1 = *(const float4*)(sp + 4);
                s16x8 w;
                w[0] = (short)f2bf(f0.x); w[1] = (short)f2bf(f0.y);
                w[2] = (short)f2bf(f0.z); w[3] = (short)f2bf(f0.w);
                w[4] = (short)f2bf(f1.x); w[5] = (short)f2bf(f1.y);
                w[6] = (short)f2bf(f1.z); w[7] = (short)f2bf(f1.w);
                *(s16x8*)dst = w;
            }
        }
        __syncthreads();
        #pragma unroll
        for (int s = 0; s < 2; ++s) {
            s16x8 afr[MR], bfr[NR];
            #pragma unroll
            for (int m = 0; m < MR; ++m) {
                const int row = rbase + m * 16 + lr;
                afr[m] = *(const s16x8*)((const char*)sA + row * 128 +
                                         (((s * 4 + lkg) ^ (row & 7)) << 4));
            }
            #pragma unroll
            for (int n = 0; n < NR; ++n) {
                const int col = cbase + n * 16 + lr;
                const int g  = ko * 8 + s * 4 + lkg;
                const int gp = (g & ~7) | ((g & 7) ^ (col & 7));
                bfr[n] = *(const s16x8*)((const char*)sB + (size_t)col * 512 + (gp << 4));
            }
            #pragma unroll
            for (int m = 0; m < MR; ++m)
                #pragma unroll
                for (int n = 0; n < NR; ++n)
                    acc[m][n] = __builtin_amdgcn_mfma_f32_16x16x32_bf16(afr[m], bfr[n], acc[m][n], 0, 0, 0);
        }
        __syncthreads();
    }

    // epilogue: C/D mapping col=lane&15, row=(lane>>4)*4+reg
    #pragma unroll
    for (int m = 0; m < MR; ++m) {
        #pragma unroll
        for (int n = 0; n < NR; ++n) {
            #pragma unroll
            for (int r = 0; r < 4; ++r) {
                const int row = m0 + rbase + m * 16 + (lane >> 4) * 4 + r;
                const int col = cbase + n * 16 + lr;
                const float v = acc[m][n][r];
                if (MODE == 0) {
                    ((unsigned short*)Cout)[(size_t)row * CH + n0 + col] = f2bf(v + bias[n0 + col]);
                } else if (MODE == 1) {
                    ((float*)Cout)[(size_t)row * CH + n0 + col] = v + bias[n0 + col];
                } else {
                    const int nb = row >> 12, q = row & 4095;
                    const float bc = (col < 64) ? bias[i * 64 + col] : bias2[i * 32 + (col - 64)];
                    ((float*)Cout)[((((size_t)nb * LVL + i) * QQ + q) * LVL + j) * 96 + col] = v + bc;
                }
            }
        }
    }
}

// Sampler: 4 queries per block (one wave each). Corner tables hold byte
// offsets (level folded in) and aw-premultiplied weights; each thread
// gathers 4 channels per corner via dwordx2.
#define SQ_ 4
__global__ __launch_bounds__(256) void sampler(
    const float* __restrict__ proj,              // (NB*LEN, 384) fp32
    const float* __restrict__ ref_pts,           // (NB, LEN, LVL, 2)
    const unsigned short* __restrict__ value,    // (NB, LEN, 256) bf16
    unsigned short* __restrict__ out_pre)        // (NB, LEN, 256) bf16
{
    const int q0 = blockIdx.x * SQ_;             // first flat query (n*LEN+iq)
    const int n  = q0 >> 14;
    const int t  = threadIdx.x;

    __shared__ float s_projf[SQ_][384];          // 6 KB
    __shared__ float s_ref  [SQ_][LVL][2];
    __shared__ float s_aw   [SQ_][NH][16];       // 2 KB
    __shared__ int   s_off  [SQ_][128][4];       // 8 KB (byte offsets)
    __shared__ float s_w    [SQ_][128][4];       // 8 KB (w * aw)

    // Phase A: stage proj rows + ref points
    {
        const float* pr = proj + (size_t)q0 * 384;
        for (int u = t; u < SQ_ * 384; u += 256)
            ((float*)s_projf)[u] = pr[u];
        if (t < SQ_ * LVL * 2)
            ((float*)s_ref)[t] = ref_pts[(size_t)q0 * LVL * 2 + t];
    }
    __syncthreads();

    // Phase B1: softmax, one thread per (q,h)
    if (t < SQ_ * NH) {
        const int q = t >> 3, h = t & 7;
        float m = -1e30f;
        #pragma unroll
        for (int j = 0; j < LVL; ++j)
            #pragma unroll
            for (int p = 0; p < PP; ++p)
                m = fmaxf(m, s_projf[q][j * 96 + 64 + h * 4 + p]);
        float e[16];
        float s = 0.f;
        #pragma unroll
        for (int j = 0; j < LVL; ++j)
            #pragma unroll
            for (int p = 0; p < PP; ++p) {
                const float v = __expf(s_projf[q][j * 96 + 64 + h * 4 + p] - m);
                e[j * 4 + p] = v;
                s += v;
            }
        const float inv = 1.f / s;
        #pragma unroll
        for (int j = 0; j < LVL; ++j)
            #pragma unroll
            for (int p = 0; p < PP; ++p)
                s_aw[q][h][j * 4 + p] = e[j * 4 + p] * inv;
    }
    __syncthreads();

    // Phase B2: corner tables, items (q,l,p,h)
    for (int e = t; e < SQ_ * 128; e += 256) {
        const int q = e >> 7, r = e & 127;
        const int l = r >> 5, p = (r >> 3) & 3, h = r & 7;
        const float ox = s_projf[q][l * 96 + h * 8 + p * 2 + 0];
        const float oy = s_projf[q][l * 96 + h * 8 + p * 2 + 1];
        const float aw = s_aw[q][h][l * 4 + p];
        const float px = s_ref[q][l][0] * (float)WL + ox - 0.5f;
        const float py = s_ref[q][l][1] * (float)HL + oy - 0.5f;
        const float x0f = floorf(px), y0f = floorf(py);
        const float dx = px - x0f,   dy = py - y0f;
        const int   x0 = (int)x0f,   y0 = (int)y0f;
        #pragma unroll
        for (int c = 0; c < 4; ++c) {
            const int cx = c & 1, cy = c >> 1;
            const int gx = x0 + cx, gy = y0 + cy;
            const bool valid = ((unsigned)gx < (unsigned)WL) && ((unsigned)gy < (unsigned)HL);
            const int cgx = min(max(gx, 0), WL - 1);
            const int cgy = min(max(gy, 0), HL - 1);
            const float w = (cx ? dx : 1.f - dx) * (cy ? dy : 1.f - dy);
            s_off[q][r][c] = (l * QQ + cgy * WL + cgx) * (CH * 2);
            s_w  [q][r][c] = valid ? w * aw : 0.f;
        }
    }
    __syncthreads();

    // Main: wave = query; lane = (h, d4); 4 channels/thread via dwordx2
    const int q  = t >> 6;
    const int h  = (t >> 3) & 7;
    const int d4 = t & 7;
    const unsigned chan = (unsigned)(h * 64 + d4 * 8);   // byte offset of 4 ch
    const char* vb8 = (const char*)(value + (size_t)n * LEN * CH);

    float acc0 = 0.f, acc1 = 0.f, acc2 = 0.f, acc3 = 0.f;
    #pragma unroll
    for (int l = 0; l < LVL; ++l) {
        #pragma unroll
        for (int p = 0; p < PP; ++p) {
            const int r = l * 32 + p * 8 + h;
            const int4   offs = *(const int4*)  &s_off[q][r][0];
            const float4 ws   = *(const float4*)&s_w  [q][r][0];
            {
                const uint2 g = *(const uint2*)(vb8 + ((unsigned)offs.x + chan));
                acc0 += ws.x * bflo(g.x); acc1 += ws.x * bfhi(g.x);
                acc2 += ws.x * bflo(g.y); acc3 += ws.x * bfhi(g.y);
            }
            {
                const uint2 g = *(const uint2*)(vb8 + ((unsigned)offs.y + chan));
                acc0 += ws.y * bflo(g.x); acc1 += ws.y * bfhi(g.x);
                acc2 += ws.y * bflo(g.y); acc3 += ws.y * bfhi(g.y);
            }
            {
                const uint2 g = *(const uint2*)(vb8 + ((unsigned)offs.z + chan));
                acc0 += ws.z * bflo(g.x); acc1 += ws.z * bfhi(g.x);
                acc2 += ws.z * bflo(g.y); acc3 += ws.z * bfhi(g.y);
            }
            {
                const uint2 g = *(const uint2*)(vb8 + ((unsigned)offs.w + chan));
                acc0 += ws.w * bflo(g.x); acc1 += ws.w * bfhi(g.x);
                acc2 += ws.w * bflo(g.y); acc3 += ws.w * bfhi(g.y);
            }
        }
    }

    const unsigned r0 = (unsigned)f2bf(acc0) | ((unsigned)f2bf(acc1) << 16);
    const unsigned r1 = (unsigned)f2bf(acc2) | ((unsigned)f2bf(acc3) << 16);
    uint2 st; st.x = r0; st.y = r1;
    *(uint2*)(out_pre + (size_t)(q0 + q) * CH + h * DD + d4 * 4) = st;
}

extern "C" void kernel_launch(void* const* d_in, const int* in_sizes, int n_in,
                              void* d_out, int out_size, void* d_ws, size_t ws_size,
                              hipStream_t stream) {
    const float* seq_query = (const float*)d_in[0];
    const float* ref_pts   = (const float*)d_in[1];
    const float* input_fl  = (const float*)d_in[2];
    const float* W_off     = (const float*)d_in[3];
    const float* b_off     = (const float*)d_in[4];
    const float* W_attn    = (const float*)d_in[5];
    const float* b_attn    = (const float*)d_in[6];
    const float* W_val     = (const float*)d_in[7];
    const float* b_val     = (const float*)d_in[8];
    const float* W_out     = (const float*)d_in[9];
    const float* b_out     = (const float*)d_in[10];

    float* out = (float*)d_out;

    unsigned short* value   = (unsigned short*)d_ws;                 // 16.8 MB
    unsigned short* out_pre = value + (size_t)NB * LEN * CH;         // 16.8 MB
    short* WT_val  = (short*)(out_pre + (size_t)NB * LEN * CH);      // 128 KB
    short* WT_out  = WT_val + 65536;                                 // 128 KB
    short* WT_proj = WT_out + 65536;                                 // 192 KB
    float* proj    = (float*)(WT_proj + 4 * 96 * 256);               // 50.3 MB

    // 0) weight prep: bf16, transposed, pre-swizzled
    prep_w<<<896, 256, 0, stream>>>(W_val, W_out, W_off, W_attn, WT_val, WT_out, WT_proj);

    // 1) value projection (fp32 in -> bf16 out)
    gemm_mfma<0, 64, 2, 4, 2><<<dim3(256, 4), 256, 0, stream>>>(
        input_fl, WT_val, b_val, nullptr, value);

    // 2) offset/attn projection (16 GEMMs, fp32 in -> fp32 proj)
    gemm_mfma<2, 96, 1, 2, 6><<<dim3(64, 16), 256, 0, stream>>>(
        seq_query, WT_proj, b_off, b_attn, proj);

    // 3) softmax + bilinear sampling (bf16 value -> bf16 out_pre)
    sampler<<<(NB * LEN) / SQ_, 256, 0, stream>>>(proj, ref_pts, value, out_pre);

    // 4) output projection (bf16 in -> fp32 d_out)
    gemm_mfma<1, 64, 2, 4, 2><<<dim3(256, 4), 256, 0, stream>>>(
        out_pre, WT_out, b_out, nullptr, out);
}

// Round 5
// 175.868 us; speedup vs baseline: 7.4247x; 1.0841x over previous
//
#include <hip/hip_runtime.h>
#include <math.h>

#define NB   2
#define LVL  4
#define QQ   4096
#define LEN  16384   // LVL*QQ
#define CH   256
#define NH   8
#define DD   32
#define PP   4
#define HL   64
#define WL   64

typedef float f32x4 __attribute__((ext_vector_type(4)));
typedef short s16x8 __attribute__((ext_vector_type(8)));

__device__ __forceinline__ unsigned short f2bf(float f) {
    union { float f; unsigned u; } v; v.f = f;
    unsigned r = v.u + 0x7FFFu + ((v.u >> 16) & 1u);
    return (unsigned short)(r >> 16);
}
__device__ __forceinline__ float bf2f(unsigned short b) {
    union { unsigned u; float f; } v; v.u = ((unsigned)b) << 16; return v.f;
}
__device__ __forceinline__ float bflo(unsigned u) {
    union { unsigned x; float f; } v; v.x = u << 16; return v.f;
}
__device__ __forceinline__ float bfhi(unsigned u) {
    union { unsigned x; float f; } v; v.x = u & 0xFFFF0000u; return v.f;
}

// Convert weights to bf16, transposed to [N][K], 16B-groups XOR-swizzled:
// WT[c][ (g&~7)|((g&7)^(c&7)) *8 + e ] = W[g*8+e][c]
__global__ __launch_bounds__(256) void prep_w(
    const float* __restrict__ W_val, const float* __restrict__ W_out,
    const float* __restrict__ W_off, const float* __restrict__ W_attn,
    short* __restrict__ WT_val, short* __restrict__ WT_out, short* __restrict__ WT_proj)
{
    const int id = blockIdx.x * 256 + threadIdx.x;   // 0 .. 229375
    if (id < 131072) {
        const int which = id >> 16;          // 0: W_val, 1: W_out
        const int u = id & 65535;
        const int c = u >> 8;                // WT row (output col), 0..255
        const int p = u & 255;               // stored position
        const int gp = p >> 3, e = p & 7;
        const int g = (gp & ~7) | ((gp & 7) ^ (c & 7));
        const int k = g * 8 + e;
        const float* W = which ? W_out : W_val;
        short* WT = which ? WT_out : WT_val;
        WT[(size_t)c * 256 + p] = (short)f2bf(W[(size_t)k * 256 + c]);
    } else {
        const int u = id - 131072;           // 0 .. 98303
        const int i = u / (96 * 256);
        const int r = u % (96 * 256);
        const int c = r >> 8;                // 0..95
        const int p = r & 255;
        const int gp = p >> 3, e = p & 7;
        const int g = (gp & ~7) | ((gp & 7) ^ (c & 7));
        const int k = g * 8 + e;
        float w;
        if (c < 64) w = W_off[((size_t)i * 256 + k) * 64 + c];
        else        w = W_attn[((size_t)i * 256 + k) * 32 + (c - 64)];
        WT_proj[((size_t)i * 96 + c) * 256 + p] = (short)f2bf(w);
    }
}

// MFMA GEMM: C[M,N] = A[M,256] @ W[256,N] + bias.  BM=128, BK=64, B LDS-resident.
// MODE 0: A fp32, C bf16 (value proj, N=256 via blockIdx.y slices of 64)
// MODE 1: A bf16, C fp32 (out proj)
// MODE 2: A fp32 = seq_query[ij], C fp32 proj layout, N=96 (blockIdx.y = ij)
// MODE 3: A = bf16(Ain) + bf16(Ain2) summed in fp32, C fp32 (out proj w/ partials)
template<int MODE, int BN, int WN, int MR, int NR>
__global__ __launch_bounds__(256) void gemm_mfma(
    const void* __restrict__ Ain, const void* __restrict__ Ain2,
    const short* __restrict__ WT,
    const float* __restrict__ bias, const float* __restrict__ bias2,
    void* __restrict__ Cout)
{
    __shared__ short sA[128 * 64];     // 16 KB, XOR-swizzled
    __shared__ short sB[BN * 256];     // pre-swizzled rows [col][K]
    const int t    = threadIdx.x;
    const int lane = t & 63;
    const int wave = t >> 6;
    const int m0   = blockIdx.x * 128;

    int i = 0, j = 0, n0 = 0;
    const float*          Af  = (const float*)Ain;
    const unsigned short* Ab  = (const unsigned short*)Ain;
    const unsigned short* Ab2 = (const unsigned short*)Ain2;
    const short*          wt  = WT;
    if (MODE == 2) {
        const int ij = blockIdx.y;
        i = ij >> 2; j = ij & 3;
        Af += (size_t)ij * (NB * QQ) * CH;
        wt += (size_t)i * 96 * 256;
    } else {
        n0 = blockIdx.y * BN;
        wt += (size_t)n0 * 256;
    }

    // stage B once (whole K), linear copy of pre-swizzled rows
    for (int u = t; u < BN * 32; u += 256)
        *(int4*)(sB + (size_t)u * 8) = *(const int4*)(wt + (size_t)u * 8);

    f32x4 acc[MR][NR];
    #pragma unroll
    for (int m = 0; m < MR; ++m)
        #pragma unroll
        for (int n = 0; n < NR; ++n)
            acc[m][n] = (f32x4){0.f, 0.f, 0.f, 0.f};

    const int wr = wave / WN;
    const int wc = wave % WN;
    const int rbase = wr * MR * 16;
    const int cbase = wc * NR * 16;
    const int lr  = lane & 15;
    const int lkg = lane >> 4;

    for (int ko = 0; ko < 4; ++ko) {
        // stage A[128][64] bf16 swizzled (fused convert for fp32 sources)
        #pragma unroll
        for (int v = 0; v < 4; ++v) {
            const int u = t + v * 256;
            const int row = u >> 3, g = u & 7;
            char* dst = (char*)sA + row * 128 + ((g ^ (row & 7)) << 4);
            const size_t aidx = (size_t)(m0 + row) * CH + ko * 64 + g * 8;
            if (MODE == 1) {
                *(int4*)dst = *(const int4*)(Ab + aidx);
            } else if (MODE == 3) {
                const s16x8 a0 = *(const s16x8*)(Ab + aidx);
                const s16x8 a1 = *(const s16x8*)(Ab2 + aidx);
                s16x8 w;
                #pragma unroll
                for (int e = 0; e < 8; ++e)
                    w[e] = (short)f2bf(bf2f((unsigned short)a0[e]) +
                                       bf2f((unsigned short)a1[e]));
                *(s16x8*)dst = w;
            } else {
                const float* sp = Af + aidx;
                const float4 f0 = *(const float4*)sp;
                const float4 f1 = *(const float4*)(sp + 4);
                s16x8 w;
                w[0] = (short)f2bf(f0.x); w[1] = (short)f2bf(f0.y);
                w[2] = (short)f2bf(f0.z); w[3] = (short)f2bf(f0.w);
                w[4] = (short)f2bf(f1.x); w[5] = (short)f2bf(f1.y);
                w[6] = (short)f2bf(f1.z); w[7] = (short)f2bf(f1.w);
                *(s16x8*)dst = w;
            }
        }
        __syncthreads();
        #pragma unroll
        for (int s = 0; s < 2; ++s) {
            s16x8 afr[MR], bfr[NR];
            #pragma unroll
            for (int m = 0; m < MR; ++m) {
                const int row = rbase + m * 16 + lr;
                afr[m] = *(const s16x8*)((const char*)sA + row * 128 +
                                         (((s * 4 + lkg) ^ (row & 7)) << 4));
            }
            #pragma unroll
            for (int n = 0; n < NR; ++n) {
                const int col = cbase + n * 16 + lr;
                const int g  = ko * 8 + s * 4 + lkg;
                const int gp = (g & ~7) | ((g & 7) ^ (col & 7));
                bfr[n] = *(const s16x8*)((const char*)sB + (size_t)col * 512 + (gp << 4));
            }
            #pragma unroll
            for (int m = 0; m < MR; ++m)
                #pragma unroll
                for (int n = 0; n < NR; ++n)
                    acc[m][n] = __builtin_amdgcn_mfma_f32_16x16x32_bf16(afr[m], bfr[n], acc[m][n], 0, 0, 0);
        }
        __syncthreads();
    }

    // epilogue: C/D mapping col=lane&15, row=(lane>>4)*4+reg
    #pragma unroll
    for (int m = 0; m < MR; ++m) {
        #pragma unroll
        for (int n = 0; n < NR; ++n) {
            #pragma unroll
            for (int r = 0; r < 4; ++r) {
                const int row = m0 + rbase + m * 16 + (lane >> 4) * 4 + r;
                const int col = cbase + n * 16 + lr;
                const float v = acc[m][n][r];
                if (MODE == 0) {
                    ((unsigned short*)Cout)[(size_t)row * CH + n0 + col] = f2bf(v + bias[n0 + col]);
                } else if (MODE == 1 || MODE == 3) {
                    ((float*)Cout)[(size_t)row * CH + n0 + col] = v + bias[n0 + col];
                } else {
                    const int nb = row >> 12, q = row & 4095;
                    const float bc = (col < 64) ? bias[i * 64 + col] : bias2[i * 32 + (col - 64)];
                    ((float*)Cout)[((((size_t)nb * LVL + i) * QQ + q) * LVL + j) * 96 + col] = v + bc;
                }
            }
        }
    }
}

// Sampler, level-pair split + XCD pinning.
// Block bid: x=bid&7 -> combo=x&3 (n=combo>>1, lp=combo&3&1), rep=x>>2;
// chunk=(bid>>3)*2+rep; 4 queries iq0=chunk*4 of batch n; levels {2lp, 2lp+1}.
// Each XCD's combo is fixed -> gathers confined to a 4MB value slice.
#define SQ_ 4
__global__ __launch_bounds__(256) void sampler(
    const float* __restrict__ proj,              // (NB*LEN, 384) fp32
    const float* __restrict__ ref_pts,           // (NB, LEN, LVL, 2)
    const unsigned short* __restrict__ value,    // (NB, LEN, 256) bf16
    unsigned short* __restrict__ out_lp0,        // partial, levels 0-1
    unsigned short* __restrict__ out_lp1)        // partial, levels 2-3
{
    const int bid   = blockIdx.x;
    const int x     = bid & 7;
    const int combo = x & 3;
    const int rep   = x >> 2;
    const int n     = combo >> 1;
    const int lp    = combo & 1;
    const int l0    = lp * 2;
    const int chunk = (bid >> 3) * 2 + rep;      // 0..4095
    const int iq0   = chunk * SQ_;               // 0..16380
    const int qf0   = n * LEN + iq0;             // flat query base
    const int t     = threadIdx.x;

    __shared__ float s_po [SQ_][128];            // offsets, 2 levels x 64
    __shared__ float s_at [SQ_][128];            // attn logits, all 4 levels
    __shared__ float s_ref[SQ_][2][2];
    __shared__ float s_aw [SQ_][NH][8];          // aw for the 2 levels
    __shared__ int   s_off[SQ_][64][4];          // byte offsets
    __shared__ float s_w  [SQ_][64][4];          // w * aw (0 if invalid)

    // Phase A: stage proj segments + ref points
    for (int u = t; u < SQ_ * 256; u += 256) {
        const int q = u >> 8, w = u & 255;
        const float* pr = proj + (size_t)(qf0 + q) * 384;
        if (w < 128) {
            const int ll = w >> 6, col = w & 63;
            s_po[q][w] = pr[(l0 + ll) * 96 + col];
        } else {
            const int v = w - 128;
            const int jj = v >> 5, c = v & 31;
            s_at[q][v] = pr[jj * 96 + 64 + c];
        }
    }
    if (t < SQ_ * 4) {
        const int q = t >> 2, ll = (t >> 1) & 1, xy = t & 1;
        s_ref[q][ll][xy] = ref_pts[((size_t)(qf0 + q) * LVL + l0 + ll) * 2 + xy];
    }
    __syncthreads();

    // Phase B1: softmax, one thread per (q,h); keep aw of our 2 levels
    if (t < SQ_ * NH) {
        const int q = t >> 3, h = t & 7;
        float m = -1e30f;
        #pragma unroll
        for (int jj = 0; jj < LVL; ++jj)
            #pragma unroll
            for (int p = 0; p < PP; ++p)
                m = fmaxf(m, s_at[q][jj * 32 + h * 4 + p]);
        float s = 0.f;
        float e[16];
        #pragma unroll
        for (int jj = 0; jj < LVL; ++jj)
            #pragma unroll
            for (int p = 0; p < PP; ++p) {
                const float v = __expf(s_at[q][jj * 32 + h * 4 + p] - m);
                e[jj * 4 + p] = v;
                s += v;
            }
        const float inv = 1.f / s;
        #pragma unroll
        for (int ll = 0; ll < 2; ++ll)
            #pragma unroll
            for (int p = 0; p < PP; ++p)
                s_aw[q][h][ll * 4 + p] = e[(l0 + ll) * 4 + p] * inv;
    }
    __syncthreads();

    // Phase B2: corner tables, items (q,ll,p,h)
    if (t < SQ_ * 64) {
        const int q = t >> 6, r = t & 63;
        const int ll = r >> 5, p = (r >> 3) & 3, h = r & 7;
        const float ox = s_po[q][ll * 64 + h * 8 + p * 2 + 0];
        const float oy = s_po[q][ll * 64 + h * 8 + p * 2 + 1];
        const float aw = s_aw[q][h][ll * 4 + p];
        const float px = s_ref[q][ll][0] * (float)WL + ox - 0.5f;
        const float py = s_ref[q][ll][1] * (float)HL + oy - 0.5f;
        const float x0f = floorf(px), y0f = floorf(py);
        const float dx = px - x0f,   dy = py - y0f;
        const int   x0 = (int)x0f,   y0 = (int)y0f;
        #pragma unroll
        for (int c = 0; c < 4; ++c) {
            const int cx = c & 1, cy = c >> 1;
            const int gx = x0 + cx, gy = y0 + cy;
            const bool valid = ((unsigned)gx < (unsigned)WL) && ((unsigned)gy < (unsigned)HL);
            const int cgx = min(max(gx, 0), WL - 1);
            const int cgy = min(max(gy, 0), HL - 1);
            const float w = (cx ? dx : 1.f - dx) * (cy ? dy : 1.f - dy);
            s_off[q][r][c] = ((l0 + ll) * QQ + cgy * WL + cgx) * (CH * 2);
            s_w  [q][r][c] = valid ? w * aw : 0.f;
        }
    }
    __syncthreads();

    // Main: wave = query; lane = (h, d4); 2 levels x 4 points x 4 corners
    const int q  = t >> 6;
    const int h  = (t >> 3) & 7;
    const int d4 = t & 7;
    const unsigned chan = (unsigned)(h * 64 + d4 * 8);   // byte offset of 4 ch
    const char* vb8 = (const char*)(value + (size_t)n * LEN * CH);

    float acc0 = 0.f, acc1 = 0.f, acc2 = 0.f, acc3 = 0.f;
    #pragma unroll
    for (int ll = 0; ll < 2; ++ll) {
        #pragma unroll
        for (int p = 0; p < PP; ++p) {
            const int r = ll * 32 + p * 8 + h;
            const int4   offs = *(const int4*)  &s_off[q][r][0];
            const float4 ws   = *(const float4*)&s_w  [q][r][0];
            {
                const uint2 g = *(const uint2*)(vb8 + ((unsigned)offs.x + chan));
                acc0 += ws.x * bflo(g.x); acc1 += ws.x * bfhi(g.x);
                acc2 += ws.x * bflo(g.y); acc3 += ws.x * bfhi(g.y);
            }
            {
                const uint2 g = *(const uint2*)(vb8 + ((unsigned)offs.y + chan));
                acc0 += ws.y * bflo(g.x); acc1 += ws.y * bfhi(g.x);
                acc2 += ws.y * bflo(g.y); acc3 += ws.y * bfhi(g.y);
            }
            {
                const uint2 g = *(const uint2*)(vb8 + ((unsigned)offs.z + chan));
                acc0 += ws.z * bflo(g.x); acc1 += ws.z * bfhi(g.x);
                acc2 += ws.z * bflo(g.y); acc3 += ws.z * bfhi(g.y);
            }
            {
                const uint2 g = *(const uint2*)(vb8 + ((unsigned)offs.w + chan));
                acc0 += ws.w * bflo(g.x); acc1 += ws.w * bfhi(g.x);
                acc2 += ws.w * bflo(g.y); acc3 += ws.w * bfhi(g.y);
            }
        }
    }

    unsigned short* outp = lp ? out_lp1 : out_lp0;
    const unsigned r0 = (unsigned)f2bf(acc0) | ((unsigned)f2bf(acc1) << 16);
    const unsigned r1 = (unsigned)f2bf(acc2) | ((unsigned)f2bf(acc3) << 16);
    uint2 st; st.x = r0; st.y = r1;
    *(uint2*)(outp + (size_t)(qf0 + q) * CH + h * DD + d4 * 4) = st;
}

extern "C" void kernel_launch(void* const* d_in, const int* in_sizes, int n_in,
                              void* d_out, int out_size, void* d_ws, size_t ws_size,
                              hipStream_t stream) {
    const float* seq_query = (const float*)d_in[0];
    const float* ref_pts   = (const float*)d_in[1];
    const float* input_fl  = (const float*)d_in[2];
    const float* W_off     = (const float*)d_in[3];
    const float* b_off     = (const float*)d_in[4];
    const float* W_attn    = (const float*)d_in[5];
    const float* b_attn    = (const float*)d_in[6];
    const float* W_val     = (const float*)d_in[7];
    const float* b_val     = (const float*)d_in[8];
    const float* W_out     = (const float*)d_in[9];
    const float* b_out     = (const float*)d_in[10];

    float* out = (float*)d_out;

    unsigned short* value   = (unsigned short*)d_ws;                 // 16.8 MB
    unsigned short* out_lp0 = value   + (size_t)NB * LEN * CH;       // 16.8 MB
    unsigned short* out_lp1 = out_lp0 + (size_t)NB * LEN * CH;       // 16.8 MB
    short* WT_val  = (short*)(out_lp1 + (size_t)NB * LEN * CH);      // 128 KB
    short* WT_out  = WT_val + 65536;                                 // 128 KB
    short* WT_proj = WT_out + 65536;                                 // 192 KB
    float* proj    = (float*)(WT_proj + 4 * 96 * 256);               // 50.3 MB

    // 0) weight prep: bf16, transposed, pre-swizzled
    prep_w<<<896, 256, 0, stream>>>(W_val, W_out, W_off, W_attn, WT_val, WT_out, WT_proj);

    // 1) value projection (fp32 in -> bf16 out)
    gemm_mfma<0, 64, 2, 4, 2><<<dim3(256, 4), 256, 0, stream>>>(
        input_fl, nullptr, WT_val, b_val, nullptr, value);

    // 2) offset/attn projection (16 GEMMs, fp32 in -> fp32 proj)
    gemm_mfma<2, 96, 1, 2, 6><<<dim3(64, 16), 256, 0, stream>>>(
        seq_query, nullptr, WT_proj, b_off, b_attn, proj);

    // 3) softmax + bilinear sampling, level-pair split (partials)
    sampler<<<(NB * LEN) / SQ_ * 2, 256, 0, stream>>>(
        proj, ref_pts, value, out_lp0, out_lp1);

    // 4) output projection (sum of partials, bf16 in -> fp32 d_out)
    gemm_mfma<3, 64, 2, 4, 2><<<dim3(256, 4), 256, 0, stream>>>(
        out_lp0, out_lp1, WT_out, b_out, nullptr, out);
}

// Round 6
// 165.527 us; speedup vs baseline: 7.8885x; 1.0625x over previous
//
#include <hip/hip_runtime.h>
#include <math.h>

#define NB   2
#define LVL  4
#define QQ   4096
#define LEN  16384   // LVL*QQ
#define CH   256
#define NH   8
#define DD   32
#define PP   4
#define HL   64
#define WL   64

typedef float    f32x4 __attribute__((ext_vector_type(4)));
typedef _Float16 h16x8 __attribute__((ext_vector_type(8)));
typedef _Float16 h16x2 __attribute__((ext_vector_type(2)));

__device__ __forceinline__ short h2s(_Float16 h) {
    union { _Float16 h; short s; } v; v.h = h; return v.s;
}
__device__ __forceinline__ _Float16 s2h(short s) {
    union { short s; _Float16 h; } v; v.s = s; return v.h;
}
__device__ __forceinline__ h16x2 u2h2(unsigned u) {
    union { unsigned u; h16x2 h; } v; v.u = u; return v.h;
}
__device__ __forceinline__ unsigned h22u(h16x2 h) {
    union { h16x2 h; unsigned u; } v; v.h = h; return v.u;
}

// Convert weights to fp16, transposed to [N][K], 16B-groups XOR-swizzled:
// WT[c][ (g&~7)|((g&7)^(c&7)) *8 + e ] = W[g*8+e][c]
__global__ __launch_bounds__(256) void prep_w(
    const float* __restrict__ W_val, const float* __restrict__ W_out,
    const float* __restrict__ W_off, const float* __restrict__ W_attn,
    short* __restrict__ WT_val, short* __restrict__ WT_out, short* __restrict__ WT_proj)
{
    const int id = blockIdx.x * 256 + threadIdx.x;   // 0 .. 229375
    if (id < 131072) {
        const int which = id >> 16;          // 0: W_val, 1: W_out
        const int u = id & 65535;
        const int c = u >> 8;                // WT row (output col), 0..255
        const int p = u & 255;               // stored position
        const int gp = p >> 3, e = p & 7;
        const int g = (gp & ~7) | ((gp & 7) ^ (c & 7));
        const int k = g * 8 + e;
        const float* W = which ? W_out : W_val;
        short* WT = which ? WT_out : WT_val;
        WT[(size_t)c * 256 + p] = h2s((_Float16)W[(size_t)k * 256 + c]);
    } else {
        const int u = id - 131072;           // 0 .. 98303
        const int i = u / (96 * 256);
        const int r = u % (96 * 256);
        const int c = r >> 8;                // 0..95
        const int p = r & 255;
        const int gp = p >> 3, e = p & 7;
        const int g = (gp & ~7) | ((gp & 7) ^ (c & 7));
        const int k = g * 8 + e;
        float w;
        if (c < 64) w = W_off[((size_t)i * 256 + k) * 64 + c];
        else        w = W_attn[((size_t)i * 256 + k) * 32 + (c - 64)];
        WT_proj[((size_t)i * 96 + c) * 256 + p] = h2s((_Float16)w);
    }
}

// MFMA GEMM (f16): C[M,N] = A[M,256] @ W[256,N] + bias.  BM=128, BK=64.
// MODE 0: A fp32, C fp16 (value proj)
// MODE 2: A fp32 = seq_query[ij], C fp16 proj layout, N=96 (blockIdx.y = ij)
// MODE 3: A = f16(Ain)+f16(Ain2) summed fp32, C fp32 (out proj w/ partials)
template<int MODE, int BN, int WN, int MR, int NR>
__global__ __launch_bounds__(256) void gemm_mfma(
    const void* __restrict__ Ain, const void* __restrict__ Ain2,
    const short* __restrict__ WT,
    const float* __restrict__ bias, const float* __restrict__ bias2,
    void* __restrict__ Cout)
{
    __shared__ short sA[128 * 64];     // 16 KB, XOR-swizzled
    __shared__ short sB[BN * 256];     // pre-swizzled rows [col][K]
    const int t    = threadIdx.x;
    const int lane = t & 63;
    const int wave = t >> 6;
    const int m0   = blockIdx.x * 128;

    int i = 0, j = 0, n0 = 0;
    const float* Af  = (const float*)Ain;
    const short* Ah  = (const short*)Ain;
    const short* Ah2 = (const short*)Ain2;
    const short* wt  = WT;
    if (MODE == 2) {
        const int ij = blockIdx.y;
        i = ij >> 2; j = ij & 3;
        Af += (size_t)ij * (NB * QQ) * CH;
        wt += (size_t)i * 96 * 256;
    } else {
        n0 = blockIdx.y * BN;
        wt += (size_t)n0 * 256;
    }

    // stage B once (whole K), linear copy of pre-swizzled rows
    for (int u = t; u < BN * 32; u += 256)
        *(int4*)(sB + (size_t)u * 8) = *(const int4*)(wt + (size_t)u * 8);

    f32x4 acc[MR][NR];
    #pragma unroll
    for (int m = 0; m < MR; ++m)
        #pragma unroll
        for (int n = 0; n < NR; ++n)
            acc[m][n] = (f32x4){0.f, 0.f, 0.f, 0.f};

    const int wr = wave / WN;
    const int wc = wave % WN;
    const int rbase = wr * MR * 16;
    const int cbase = wc * NR * 16;
    const int lr  = lane & 15;
    const int lkg = lane >> 4;

    for (int ko = 0; ko < 4; ++ko) {
        // stage A[128][64] f16 swizzled (fused convert for fp32 sources)
        #pragma unroll
        for (int v = 0; v < 4; ++v) {
            const int u = t + v * 256;
            const int row = u >> 3, g = u & 7;
            char* dst = (char*)sA + row * 128 + ((g ^ (row & 7)) << 4);
            const size_t aidx = (size_t)(m0 + row) * CH + ko * 64 + g * 8;
            if (MODE == 3) {
                const h16x8 a0 = *(const h16x8*)(Ah  + aidx);
                const h16x8 a1 = *(const h16x8*)(Ah2 + aidx);
                h16x8 w;
                #pragma unroll
                for (int e = 0; e < 8; ++e)
                    w[e] = (_Float16)((float)a0[e] + (float)a1[e]);
                *(h16x8*)dst = w;
            } else {
                const float* sp = Af + aidx;
                const float4 f0 = *(const float4*)sp;
                const float4 f1 = *(const float4*)(sp + 4);
                h16x8 w;
                w[0] = (_Float16)f0.x; w[1] = (_Float16)f0.y;
                w[2] = (_Float16)f0.z; w[3] = (_Float16)f0.w;
                w[4] = (_Float16)f1.x; w[5] = (_Float16)f1.y;
                w[6] = (_Float16)f1.z; w[7] = (_Float16)f1.w;
                *(h16x8*)dst = w;
            }
        }
        __syncthreads();
        #pragma unroll
        for (int s = 0; s < 2; ++s) {
            h16x8 afr[MR], bfr[NR];
            #pragma unroll
            for (int m = 0; m < MR; ++m) {
                const int row = rbase + m * 16 + lr;
                afr[m] = *(const h16x8*)((const char*)sA + row * 128 +
                                         (((s * 4 + lkg) ^ (row & 7)) << 4));
            }
            #pragma unroll
            for (int n = 0; n < NR; ++n) {
                const int col = cbase + n * 16 + lr;
                const int g  = ko * 8 + s * 4 + lkg;
                const int gp = (g & ~7) | ((g & 7) ^ (col & 7));
                bfr[n] = *(const h16x8*)((const char*)sB + (size_t)col * 512 + (gp << 4));
            }
            #pragma unroll
            for (int m = 0; m < MR; ++m)
                #pragma unroll
                for (int n = 0; n < NR; ++n)
                    acc[m][n] = __builtin_amdgcn_mfma_f32_16x16x32_f16(afr[m], bfr[n], acc[m][n], 0, 0, 0);
        }
        __syncthreads();
    }

    // epilogue: C/D mapping col=lane&15, row=(lane>>4)*4+reg
    #pragma unroll
    for (int m = 0; m < MR; ++m) {
        #pragma unroll
        for (int n = 0; n < NR; ++n) {
            #pragma unroll
            for (int r = 0; r < 4; ++r) {
                const int row = m0 + rbase + m * 16 + (lane >> 4) * 4 + r;
                const int col = cbase + n * 16 + lr;
                const float v = acc[m][n][r];
                if (MODE == 0) {
                    ((short*)Cout)[(size_t)row * CH + n0 + col] = h2s((_Float16)(v + bias[n0 + col]));
                } else if (MODE == 3) {
                    ((float*)Cout)[(size_t)row * CH + n0 + col] = v + bias[n0 + col];
                } else {
                    const int nb = row >> 12, q = row & 4095;
                    const float bc = (col < 64) ? bias[i * 64 + col] : bias2[i * 32 + (col - 64)];
                    ((short*)Cout)[((((size_t)nb * LVL + i) * QQ + q) * LVL + j) * 96 + col] = h2s((_Float16)(v + bc));
                }
            }
        }
    }
}

// Sampler: level-pair split + XCD pinning; 8 queries per block, 2 per wave.
// lane = (qsub, h, d8): each thread gathers 8 fp16 channels per corner via
// dwordx4 and accumulates with v_pk_fma_f16.
#define SQB 8
__global__ __launch_bounds__(256) void sampler(
    const short* __restrict__ proj,              // (NB*LEN, 384) fp16
    const float* __restrict__ ref_pts,           // (NB, LEN, LVL, 2)
    const short* __restrict__ value,             // (NB, LEN, 256) fp16
    short* __restrict__ out_lp0,                 // partial, levels 0-1
    short* __restrict__ out_lp1)                 // partial, levels 2-3
{
    const int bid   = blockIdx.x;
    const int x     = bid & 7;
    const int combo = x & 3;
    const int rep   = x >> 2;
    const int n     = combo >> 1;
    const int lp    = combo & 1;
    const int l0    = lp * 2;
    const int chunk = (bid >> 3) * 2 + rep;      // 0..2047
    const int iq0   = chunk * SQB;
    const int qf0   = n * LEN + iq0;             // flat query base
    const int t     = threadIdx.x;

    __shared__ short    s_raw[SQB][384];         // 6 KB fp16 proj rows
    __shared__ float    s_ref[SQB][2][2];
    __shared__ float    s_aw [SQB][NH][8];       // aw for the 2 levels
    __shared__ int      s_off[SQB][64][4];       // byte offsets
    __shared__ unsigned s_w2 [SQB][64][4];       // half2 splats of w*aw

    // Phase A: stage proj rows (coalesced dword) + ref points
    {
        const unsigned* pr = (const unsigned*)(proj + (size_t)qf0 * 384);
        for (int u = t; u < SQB * 192; u += 256)
            ((unsigned*)s_raw)[u] = pr[u];
        if (t < SQB * 4) {
            const int q = t >> 2, ll = (t >> 1) & 1, xy = t & 1;
            s_ref[q][ll][xy] = ref_pts[((size_t)(qf0 + q) * LVL + l0 + ll) * 2 + xy];
        }
    }
    __syncthreads();

    // Phase B1: softmax, one thread per (q,h); keep aw of our 2 levels
    if (t < SQB * NH) {
        const int q = t >> 3, h = t & 7;
        float lg[16];
        #pragma unroll
        for (int jj = 0; jj < LVL; ++jj)
            #pragma unroll
            for (int p = 0; p < PP; ++p)
                lg[jj * 4 + p] = (float)s2h(s_raw[q][jj * 96 + 64 + h * 4 + p]);
        float m = -1e30f;
        #pragma unroll
        for (int e = 0; e < 16; ++e) m = fmaxf(m, lg[e]);
        float s = 0.f;
        #pragma unroll
        for (int e = 0; e < 16; ++e) { lg[e] = __expf(lg[e] - m); s += lg[e]; }
        const float inv = 1.f / s;
        #pragma unroll
        for (int ll = 0; ll < 2; ++ll)
            #pragma unroll
            for (int p = 0; p < PP; ++p)
                s_aw[q][h][ll * 4 + p] = lg[(l0 + ll) * 4 + p] * inv;
    }
    __syncthreads();

    // Phase B2: corner tables, items (q,ll,p,h)
    for (int e = t; e < SQB * 64; e += 256) {
        const int q = e >> 6, r = e & 63;
        const int ll = r >> 5, p = (r >> 3) & 3, h = r & 7;
        const float ox = (float)s2h(s_raw[q][(l0 + ll) * 96 + h * 8 + p * 2 + 0]);
        const float oy = (float)s2h(s_raw[q][(l0 + ll) * 96 + h * 8 + p * 2 + 1]);
        const float aw = s_aw[q][h][ll * 4 + p];
        const float px = s_ref[q][ll][0] * (float)WL + ox - 0.5f;
        const float py = s_ref[q][ll][1] * (float)HL + oy - 0.5f;
        const float x0f = floorf(px), y0f = floorf(py);
        const float dx = px - x0f,   dy = py - y0f;
        const int   x0 = (int)x0f,   y0 = (int)y0f;
        #pragma unroll
        for (int c = 0; c < 4; ++c) {
            const int cx = c & 1, cy = c >> 1;
            const int gx = x0 + cx, gy = y0 + cy;
            const bool valid = ((unsigned)gx < (unsigned)WL) && ((unsigned)gy < (unsigned)HL);
            const int cgx = min(max(gx, 0), WL - 1);
            const int cgy = min(max(gy, 0), HL - 1);
            const float w = (cx ? dx : 1.f - dx) * (cy ? dy : 1.f - dy);
            const float wa = valid ? w * aw : 0.f;
            const _Float16 hw = (_Float16)wa;
            h16x2 hv; hv[0] = hw; hv[1] = hw;
            s_off[q][r][c] = ((l0 + ll) * QQ + cgy * WL + cgx) * (CH * 2);
            s_w2 [q][r][c] = h22u(hv);
        }
    }
    __syncthreads();

    // Main: wave = 2 queries; lane = (qsub, h, d8); 8 fp16 channels/thread
    const int lane = t & 63;
    const int wv   = t >> 6;
    const int q    = wv * 2 + (lane >> 5);
    const int h    = (lane >> 2) & 7;
    const int d8   = lane & 3;
    const unsigned chan = (unsigned)(h * 64 + d8 * 16);  // byte offset of 8 ch
    const char* vb8 = (const char*)(value + (size_t)n * LEN * CH);

    h16x2 acc0 = (h16x2)0, acc1 = (h16x2)0, acc2 = (h16x2)0, acc3 = (h16x2)0;
    #pragma unroll
    for (int ll = 0; ll < 2; ++ll) {
        #pragma unroll
        for (int p = 0; p < PP; ++p) {
            const int r = ll * 32 + p * 8 + h;
            const int4  offs = *(const int4*)&s_off[q][r][0];
            const uint4 ws   = *(const uint4*)&s_w2[q][r][0];
            {
                const uint4 g = *(const uint4*)(vb8 + ((unsigned)offs.x + chan));
                const h16x2 w = u2h2(ws.x);
                acc0 += w * u2h2(g.x); acc1 += w * u2h2(g.y);
                acc2 += w * u2h2(g.z); acc3 += w * u2h2(g.w);
            }
            {
                const uint4 g = *(const uint4*)(vb8 + ((unsigned)offs.y + chan));
                const h16x2 w = u2h2(ws.y);
                acc0 += w * u2h2(g.x); acc1 += w * u2h2(g.y);
                acc2 += w * u2h2(g.z); acc3 += w * u2h2(g.w);
            }
            {
                const uint4 g = *(const uint4*)(vb8 + ((unsigned)offs.z + chan));
                const h16x2 w = u2h2(ws.z);
                acc0 += w * u2h2(g.x); acc1 += w * u2h2(g.y);
                acc2 += w * u2h2(g.z); acc3 += w * u2h2(g.w);
            }
            {
                const uint4 g = *(const uint4*)(vb8 + ((unsigned)offs.w + chan));
                const h16x2 w = u2h2(ws.w);
                acc0 += w * u2h2(g.x); acc1 += w * u2h2(g.y);
                acc2 += w * u2h2(g.z); acc3 += w * u2h2(g.w);
            }
        }
    }

    short* outp = lp ? out_lp1 : out_lp0;
    uint4 st;
    st.x = h22u(acc0); st.y = h22u(acc1); st.z = h22u(acc2); st.w = h22u(acc3);
    *(uint4*)(outp + (size_t)(qf0 + q) * CH + h * DD + d8 * 8) = st;
}

extern "C" void kernel_launch(void* const* d_in, const int* in_sizes, int n_in,
                              void* d_out, int out_size, void* d_ws, size_t ws_size,
                              hipStream_t stream) {
    const float* seq_query = (const float*)d_in[0];
    const float* ref_pts   = (const float*)d_in[1];
    const float* input_fl  = (const float*)d_in[2];
    const float* W_off     = (const float*)d_in[3];
    const float* b_off     = (const float*)d_in[4];
    const float* W_attn    = (const float*)d_in[5];
    const float* b_attn    = (const float*)d_in[6];
    const float* W_val     = (const float*)d_in[7];
    const float* b_val     = (const float*)d_in[8];
    const float* W_out     = (const float*)d_in[9];
    const float* b_out     = (const float*)d_in[10];

    float* out = (float*)d_out;

    short* value   = (short*)d_ws;                                   // 16.8 MB
    short* out_lp0 = value   + (size_t)NB * LEN * CH;                // 16.8 MB
    short* out_lp1 = out_lp0 + (size_t)NB * LEN * CH;                // 16.8 MB
    short* WT_val  = out_lp1 + (size_t)NB * LEN * CH;                // 128 KB
    short* WT_out  = WT_val + 65536;                                 // 128 KB
    short* WT_proj = WT_out + 65536;                                 // 192 KB
    short* proj    = WT_proj + 4 * 96 * 256;                         // 25.2 MB

    // 0) weight prep: fp16, transposed, pre-swizzled
    prep_w<<<896, 256, 0, stream>>>(W_val, W_out, W_off, W_attn, WT_val, WT_out, WT_proj);

    // 1) value projection (fp32 in -> fp16 out)
    gemm_mfma<0, 64, 2, 4, 2><<<dim3(256, 4), 256, 0, stream>>>(
        input_fl, nullptr, WT_val, b_val, nullptr, value);

    // 2) offset/attn projection (16 GEMMs, fp32 in -> fp16 proj)
    gemm_mfma<2, 96, 1, 2, 6><<<dim3(64, 16), 256, 0, stream>>>(
        seq_query, nullptr, WT_proj, b_off, b_attn, proj);

    // 3) softmax + bilinear sampling, level-pair split (fp16 partials)
    sampler<<<(NB * LEN) / SQB * 2, 256, 0, stream>>>(
        proj, ref_pts, value, out_lp0, out_lp1);

    // 4) output projection (sum of partials, fp16 in -> fp32 d_out)
    gemm_mfma<3, 64, 2, 4, 2><<<dim3(256, 4), 256, 0, stream>>>(
        out_lp0, out_lp1, WT_out, b_out, nullptr, out);
}